// Round 10
// baseline (373.185 us; speedup 1.0000x reference)
//
#include <hip/hip_runtime.h>
#include <hip/hip_bf16.h>
#include <math.h>

#define N_NODES 50000
#define N_EDGES 500000
#define C_DIM 128
#define N_TILES 3125   // 50000/16 exact

#define CSR_BLOCKS 1954      // ceil(500000/256)
#define CONCAT_BLOCKS 3125   // 50000*16/256
#define PACK_BLOCKS 480      // (20*8*512 + 20*4*512)/256
#define NODE_CHUNKS 1563     // ceil(50000/32)

typedef __attribute__((ext_vector_type(8))) short bf8;
typedef __attribute__((ext_vector_type(4))) float f32x4;

__device__ __forceinline__ float bflo(unsigned u) { return __uint_as_float(u << 16); }
__device__ __forceinline__ float bfhi(unsigned u) { return __uint_as_float(u & 0xffff0000u); }
__device__ __forceinline__ unsigned short f2bfu(float f) {
    __hip_bfloat16 h = __float2bfloat16(f);
    unsigned short u;
    __builtin_memcpy(&u, &h, 2);
    return u;
}
__device__ __forceinline__ unsigned packbf(float a, float b) {
    return ((unsigned)f2bfu(b) << 16) | f2bfu(a);
}

// ---------------- graph preprocessing ----------------

__global__ void count_deg(const int* __restrict__ row, const int* __restrict__ col,
                          int* __restrict__ dout, int* __restrict__ din, int e) {
    int i = blockIdx.x * blockDim.x + threadIdx.x;
    if (i >= e) return;
    atomicAdd(&dout[row[i]], 1);
    atomicAdd(&din[col[i]], 1);
}

__global__ void scan_block(const int* __restrict__ counts, int* __restrict__ excl,
                           int* __restrict__ blocksums, int n) {
    __shared__ int tmp[1024];
    int tid = threadIdx.x;
    int gid = blockIdx.x * 1024 + tid;
    int v = (gid < n) ? counts[gid] : 0;
    tmp[tid] = v;
    __syncthreads();
    for (int off = 1; off < 1024; off <<= 1) {
        int t = (tid >= off) ? tmp[tid - off] : 0;
        __syncthreads();
        tmp[tid] += t;
        __syncthreads();
    }
    int incl = tmp[tid];
    if (gid < n) excl[gid] = incl - v;
    if (tid == 1023) blocksums[blockIdx.x] = incl;
}

__global__ void scan_sums(int* __restrict__ blocksums, int nb) {
    __shared__ int tmp[64];
    int tid = threadIdx.x;
    int v = (tid < nb) ? blocksums[tid] : 0;
    tmp[tid] = v;
    __syncthreads();
    for (int off = 1; off < 64; off <<= 1) {
        int t = (tid >= off) ? tmp[tid - off] : 0;
        __syncthreads();
        tmp[tid] += t;
        __syncthreads();
    }
    if (tid < nb) blocksums[tid] = tmp[tid] - v;
}

__global__ void scan_add(int* __restrict__ rowptr, const int* __restrict__ blocksums,
                         int* __restrict__ cursor, const int* __restrict__ dout,
                         const int* __restrict__ din, float2* __restrict__ winv,
                         int n, int e_total) {
    int gid = blockIdx.x * blockDim.x + threadIdx.x;
    if (gid < n) {
        int v = rowptr[gid] + blocksums[gid >> 10];
        rowptr[gid] = v;
        cursor[gid] = v;
        winv[gid] = make_float2(1.0f / (float)dout[gid], 1.0f / (float)din[gid]);
    }
    if (gid == n) rowptr[n] = e_total;
}

// ---------------- weight helpers ----------------
__device__ __forceinline__ float wraw(const float* W, int d, int kk, int k, int j) {
    return W[((d * 3 + kk) * 128 + k) * 64 + j];
}

__device__ __forceinline__ float zr_val(const float* Wz, const float* Wr, int k, int nn) {
    const float* W = (nn < 64) ? Wz : Wr;
    int j = nn & 63;
    if (k < 128) return wraw(W, 0, 0, k, j) + wraw(W, 1, 0, k, j);
    int k2 = k - 128;
    int kk = (k2 >= 256) ? 2 : 1;
    int k3 = k2 & 255;
    int p = k3 >> 2, sub = k3 & 3;
    return wraw(W, sub >> 1, kk, 2 * p + (sub & 1), j);
}

__device__ __forceinline__ float h_val(const float* Wh, int k, int j) {
    if (k < 64) return wraw(Wh, 0, 0, k, j) + wraw(Wh, 1, 0, k, j);
    if (k < 320) {
        int k2 = k - 64;
        int kk = (k2 >= 128) ? 2 : 1;
        int k3 = k2 & 127;
        int p = k3 >> 2, sub = k3 & 3;
        return wraw(Wh, sub >> 1, kk, 2 * p + (sub & 1), j);
    }
    if (k < 384) return wraw(Wh, 0, 0, 64 + (k - 320), j) + wraw(Wh, 1, 0, 64 + (k - 320), j);
    int k2 = k - 384;
    int kk = (k2 >= 128) ? 2 : 1;
    int k3 = k2 & 127;
    int p = k3 >> 2, sub = k3 & 3;
    return wraw(Wh, sub >> 1, kk, 64 + 2 * p + (sub & 1), j);
}

// ---------------- fused prep: build_csr + concat_xh + pack_weights ----------
// XHs: slice-major copy of XH for the sliced prop1 gather: [slice(4)][node][32 shorts]
__global__ void fused_prep(const int* __restrict__ row, const int* __restrict__ col,
                           const float2* __restrict__ winv, int* __restrict__ cursor,
                           int* __restrict__ csr_src, float2* __restrict__ csr_w,
                           const float* __restrict__ X, const float* __restrict__ Hm,
                           unsigned short* __restrict__ XH, unsigned short* __restrict__ XHp,
                           unsigned short* __restrict__ XHs,
                           const float* __restrict__ Wz, const float* __restrict__ Wr,
                           const float* __restrict__ Wh,
                           unsigned short* __restrict__ Wzrf, unsigned short* __restrict__ Whf,
                           int n, int e) {
    int b = blockIdx.x;
    if (b < CSR_BLOCKS) {
        int i = b * 256 + threadIdx.x;
        if (i >= e) return;
        int r = row[i], c = col[i];
        int pos = atomicAdd(&cursor[c], 1);
        csr_src[pos] = r;
        csr_w[pos] = winv[r];
    } else if (b < CSR_BLOCKS + CONCAT_BLOCKS) {
        int t = (b - CSR_BLOCKS) * 256 + threadIdx.x;   // < n*16 exactly
        int node = t >> 4, p = t & 15;
        const float* src = (p < 8) ? (X + (size_t)node * 64 + 8 * p)
                                   : (Hm + (size_t)node * 64 + 8 * (p - 8));
        float4 v0 = *(const float4*)src;
        float4 v1 = *(const float4*)(src + 4);
        uint4 o;
        o.x = packbf(v0.x, v0.y); o.y = packbf(v0.z, v0.w);
        o.z = packbf(v1.x, v1.y); o.w = packbf(v1.z, v1.w);
        *(uint4*)(XH + (size_t)node * 128 + 8 * p) = o;
        int tile = node >> 4, lr = node & 15, ck = p >> 2, q = p & 3;
        *(uint4*)(XHp + (((size_t)tile * 4 + ck) * 64 + q * 16 + lr) * 8) = o;
        // slice-major: slice = p>>2, offset (p&3)*8
        *(uint4*)(XHs + ((size_t)(p >> 2) * n + node) * 32 + (p & 3) * 8) = o;
    } else {
        int i = (b - CSR_BLOCKS - CONCAT_BLOCKS) * 256 + threadIdx.x;
        if (i < 20 * 8 * 64 * 8) {
            int j = i & 7, lane = (i >> 3) & 63, nt = (i >> 9) & 7, ks = i >> 12;
            int k = ks * 32 + (lane >> 4) * 8 + j;
            int nn = nt * 16 + (lane & 15);
            Wzrf[i] = f2bfu(zr_val(Wz, Wr, k, nn));
        } else if (i < 20 * 8 * 64 * 8 + 20 * 4 * 64 * 8) {
            int i2 = i - 20 * 8 * 64 * 8;
            int j = i2 & 7, lane = (i2 >> 3) & 63, nt = (i2 >> 9) & 3, ks = i2 >> 11;
            int k = ks * 32 + (lane >> 4) * 8 + j;
            int nn = nt * 16 + (lane & 15);
            Whf[i2] = f2bfu(h_val(Wh, k, nn));
        }
    }
}

// ---------------- sliced 128-col props (XCD-pinned L2-resident gathers) -----
// prop1_128s: slice a of 4 (XH cols [32a,32a+32), 3.2MB slice array in XHs).
// Wave = 8 nodes x 8 lanes; lane l covers global unit p' = 8a + l (4 cols).
// Outputs: P1g [gslice(8)][node][32] (prop2 gather layout) + P1p (packed GEMM A).
__global__ void prop1_128s(const unsigned short* __restrict__ XHs,
                           const int* __restrict__ rowptr, const int* __restrict__ src,
                           const float2* __restrict__ w,
                           unsigned short* __restrict__ P1g, unsigned short* __restrict__ P1p,
                           int n) {
    int slice = blockIdx.x & 3;          // -> XCDs {slice, slice+4} via %8 round-robin
    int chunk = blockIdx.x >> 2;
    int tid = threadIdx.x;
    int wid = tid >> 6, lane = tid & 63;
    int g = lane >> 3, l = lane & 7;
    int node = chunk * 32 + wid * 8 + g;
    if (node >= n) return;
    const unsigned short* S = XHs + (size_t)slice * n * 32;
    int beg = rowptr[node], end = rowptr[node + 1];
    float ao0 = 0.f, ao1 = 0.f, ao2 = 0.f, ao3 = 0.f;
    float ai0 = 0.f, ai1 = 0.f, ai2 = 0.f, ai3 = 0.f;
    int j = beg;
#define S1STEP(s_, w_) {                                                     \
        uint2 u = *(const uint2*)(S + (size_t)(s_) * 32 + 4 * l);            \
        float c0 = bflo(u.x), c1 = bfhi(u.x), c2 = bflo(u.y), c3 = bfhi(u.y);\
        ao0 = fmaf(w_.x, c0, ao0); ao1 = fmaf(w_.x, c1, ao1);                \
        ao2 = fmaf(w_.x, c2, ao2); ao3 = fmaf(w_.x, c3, ao3);                \
        ai0 = fmaf(w_.y, c0, ai0); ai1 = fmaf(w_.y, c1, ai1);                \
        ai2 = fmaf(w_.y, c2, ai2); ai3 = fmaf(w_.y, c3, ai3); }
    for (; j + 4 <= end; j += 4) {
        int s0 = src[j], s1 = src[j + 1], s2 = src[j + 2], s3 = src[j + 3];
        float2 w0 = w[j], w1 = w[j + 1], w2 = w[j + 2], w3 = w[j + 3];
        S1STEP(s0, w0); S1STEP(s1, w1); S1STEP(s2, w2); S1STEP(s3, w3);
    }
    for (; j < end; ++j) {
        int s = src[j]; float2 wv = w[j];
        S1STEP(s, wv);
    }
#undef S1STEP
    uint4 o;
    o.x = packbf(ao0, ao1); o.y = packbf(ai0, ai1);
    o.z = packbf(ao2, ao3); o.w = packbf(ai2, ai3);
    int pp = 8 * slice + l;              // global 8-short unit index [0,32)
    *(uint4*)(P1g + ((size_t)(pp >> 2) * n + node) * 32 + (pp & 3) * 8) = o;
    int tile = node >> 4, lr = node & 15;
    *(uint4*)(P1p + (((size_t)tile * 8 + (pp >> 2)) * 64 + (pp & 3) * 16 + lr) * 8) = o;
}

// prop2_128s: slice s of 8 (P1-row shorts [32s,32s+32), 3.2MB slice in P1g).
// Wave = 8 nodes x 8 lanes; lane l covers shorts [32s+4l, +4) = o/i for 2 cols.
__global__ void prop2_128s(const unsigned short* __restrict__ P1g,
                           const unsigned short* __restrict__ Xc,
                           const int* __restrict__ rowptr, const int* __restrict__ src,
                           const float2* __restrict__ w,
                           unsigned short* __restrict__ P2p, int n) {
    int slice = blockIdx.x & 7;          // -> XCD slice via %8 round-robin
    int chunk = blockIdx.x >> 3;
    int tid = threadIdx.x;
    int wid = tid >> 6, lane = tid & 63;
    int g = lane >> 3, l = lane & 7;
    int node = chunk * 32 + wid * 8 + g;
    if (node >= n) return;
    const unsigned short* S = P1g + (size_t)slice * n * 32;
    int beg = rowptr[node], end = rowptr[node + 1];
    float oa = 0.f, ob = 0.f, ia = 0.f, ib = 0.f;
    int j = beg;
#define S2STEP(s_, w_) {                                                     \
        uint2 v = *(const uint2*)(S + (size_t)(s_) * 32 + 4 * l);            \
        oa = fmaf(w_.x, bflo(v.x), oa); ob = fmaf(w_.x, bfhi(v.x), ob);      \
        ia = fmaf(w_.y, bflo(v.y), ia); ib = fmaf(w_.y, bfhi(v.y), ib); }
    for (; j + 4 <= end; j += 4) {
        int s0 = src[j], s1 = src[j + 1], s2 = src[j + 2], s3 = src[j + 3];
        float2 w0 = w[j], w1 = w[j + 1], w2 = w[j + 2], w3 = w[j + 3];
        S2STEP(s0, w0); S2STEP(s1, w1); S2STEP(s2, w2); S2STEP(s3, w3);
    }
    for (; j < end; ++j) {
        int s = src[j]; float2 wv = w[j];
        S2STEP(s, wv);
    }
#undef S2STEP
    // Xc cols for this lane: c0 = 16*slice + 4*(l>>1) + 2*(l&1)
    int c0 = 16 * slice + 4 * (l >> 1) + 2 * (l & 1);
    unsigned ux = *(const unsigned*)(Xc + (size_t)node * 128 + c0);
    float x0 = bflo(ux), x1 = bfhi(ux);
    uint2 o;
    o.x = packbf(2.f * oa - x0, 2.f * ob - x1);
    o.y = packbf(2.f * ia - x0, 2.f * ib - x1);
    int tile = node >> 4, lr = node & 15;
    *(uint2*)(P2p + (((size_t)tile * 8 + slice) * 64 + (l >> 1) * 16 + lr) * 8 + (l & 1) * 4) = o;
}

// ---------------- 64-col props (unchanged R9 structure) ----------------

__global__ void prop1_64(const unsigned short* __restrict__ HR,
                         const int* __restrict__ rowptr, const int* __restrict__ src,
                         const float2* __restrict__ w,
                         unsigned short* __restrict__ Q1, unsigned short* __restrict__ Q1p,
                         int n) {
    int tid = blockIdx.x * blockDim.x + threadIdx.x;
    int lane = tid & 63;
    int node = ((tid >> 6) << 2) + (lane >> 4);
    int p = lane & 15;
    if (node >= n) return;
    int beg = rowptr[node], end = rowptr[node + 1];
    float ao0 = 0.f, ao1 = 0.f, ao2 = 0.f, ao3 = 0.f;
    float ai0 = 0.f, ai1 = 0.f, ai2 = 0.f, ai3 = 0.f;
    int j = beg;
#define Q1STEP(s_, w_) {                                                     \
        uint2 u = *(const uint2*)(HR + (size_t)(s_) * 64 + 4 * p);           \
        float c0 = bflo(u.x), c1 = bfhi(u.x), c2 = bflo(u.y), c3 = bfhi(u.y);\
        ao0 = fmaf(w_.x, c0, ao0); ao1 = fmaf(w_.x, c1, ao1);                \
        ao2 = fmaf(w_.x, c2, ao2); ao3 = fmaf(w_.x, c3, ao3);                \
        ai0 = fmaf(w_.y, c0, ai0); ai1 = fmaf(w_.y, c1, ai1);                \
        ai2 = fmaf(w_.y, c2, ai2); ai3 = fmaf(w_.y, c3, ai3); }
    for (; j + 8 <= end; j += 8) {
        int s0 = src[j], s1 = src[j + 1], s2 = src[j + 2], s3 = src[j + 3];
        int s4 = src[j + 4], s5 = src[j + 5], s6 = src[j + 6], s7 = src[j + 7];
        float2 w0 = w[j], w1 = w[j + 1], w2 = w[j + 2], w3 = w[j + 3];
        float2 w4 = w[j + 4], w5 = w[j + 5], w6 = w[j + 6], w7 = w[j + 7];
        Q1STEP(s0, w0); Q1STEP(s1, w1); Q1STEP(s2, w2); Q1STEP(s3, w3);
        Q1STEP(s4, w4); Q1STEP(s5, w5); Q1STEP(s6, w6); Q1STEP(s7, w7);
    }
    for (; j + 4 <= end; j += 4) {
        int s0 = src[j], s1 = src[j + 1], s2 = src[j + 2], s3 = src[j + 3];
        float2 w0 = w[j], w1 = w[j + 1], w2 = w[j + 2], w3 = w[j + 3];
        Q1STEP(s0, w0); Q1STEP(s1, w1); Q1STEP(s2, w2); Q1STEP(s3, w3);
    }
    for (; j < end; ++j) {
        int s = src[j]; float2 wv = w[j];
        Q1STEP(s, wv);
    }
#undef Q1STEP
    uint4 o;
    o.x = packbf(ao0, ao1); o.y = packbf(ai0, ai1);
    o.z = packbf(ao2, ao3); o.w = packbf(ai2, ai3);
    *(uint4*)(Q1 + (size_t)node * 128 + 8 * p) = o;
    int tile = node >> 4, lr = node & 15, ck = p >> 2, q = p & 3;
    *(uint4*)(Q1p + (((size_t)tile * 4 + ck) * 64 + q * 16 + lr) * 8) = o;
}

__global__ void prop2_64(const unsigned short* __restrict__ Q1,
                         const unsigned short* __restrict__ HR,
                         const int* __restrict__ rowptr, const int* __restrict__ src,
                         const float2* __restrict__ w,
                         unsigned short* __restrict__ Q2p, int n) {
    int tid = blockIdx.x * blockDim.x + threadIdx.x;
    int lane = tid & 63;
    int node = ((tid >> 6) << 2) + (lane >> 4);
    int p = lane & 15;
    if (node >= n) return;
    int beg = rowptr[node], end = rowptr[node + 1];
    float oa = 0.f, ob = 0.f, oc = 0.f, od = 0.f;
    float ia = 0.f, ib = 0.f, ic = 0.f, id = 0.f;
    int j = beg;
#define Q2STEP(s_, w_) {                                                     \
        uint4 v = *(const uint4*)(Q1 + (size_t)(s_) * 128 + 8 * p);          \
        oa = fmaf(w_.x, bflo(v.x), oa); ob = fmaf(w_.x, bfhi(v.x), ob);      \
        ia = fmaf(w_.y, bflo(v.y), ia); ib = fmaf(w_.y, bfhi(v.y), ib);      \
        oc = fmaf(w_.x, bflo(v.z), oc); od = fmaf(w_.x, bfhi(v.z), od);      \
        ic = fmaf(w_.y, bflo(v.w), ic); id = fmaf(w_.y, bfhi(v.w), id); }
    for (; j + 8 <= end; j += 8) {
        int s0 = src[j], s1 = src[j + 1], s2 = src[j + 2], s3 = src[j + 3];
        int s4 = src[j + 4], s5 = src[j + 5], s6 = src[j + 6], s7 = src[j + 7];
        float2 w0 = w[j], w1 = w[j + 1], w2 = w[j + 2], w3 = w[j + 3];
        float2 w4 = w[j + 4], w5 = w[j + 5], w6 = w[j + 6], w7 = w[j + 7];
        Q2STEP(s0, w0); Q2STEP(s1, w1); Q2STEP(s2, w2); Q2STEP(s3, w3);
        Q2STEP(s4, w4); Q2STEP(s5, w5); Q2STEP(s6, w6); Q2STEP(s7, w7);
    }
    for (; j + 4 <= end; j += 4) {
        int s0 = src[j], s1 = src[j + 1], s2 = src[j + 2], s3 = src[j + 3];
        float2 w0 = w[j], w1 = w[j + 1], w2 = w[j + 2], w3 = w[j + 3];
        Q2STEP(s0, w0); Q2STEP(s1, w1); Q2STEP(s2, w2); Q2STEP(s3, w3);
    }
    for (; j < end; ++j) {
        int s = src[j]; float2 wv = w[j];
        Q2STEP(s, wv);
    }
#undef Q2STEP
    uint2 ux = *(const uint2*)(HR + (size_t)node * 64 + 4 * p);
    float xa = bflo(ux.x), xb = bfhi(ux.x), xc = bflo(ux.y), xd = bfhi(ux.y);
    uint4 o;
    o.x = packbf(2.f * oa - xa, 2.f * ob - xb);
    o.y = packbf(2.f * ia - xa, 2.f * ib - xb);
    o.z = packbf(2.f * oc - xc, 2.f * od - xd);
    o.w = packbf(2.f * ic - xc, 2.f * id - xd);
    int tile = node >> 4, lr = node & 15, ck = p >> 2, q = p & 3;
    *(uint4*)(Q2p + (((size_t)tile * 4 + ck) * 64 + q * 16 + lr) * 8) = o;
}

// ---------------- MFMA GEMMs (unchanged R9) ----------------

__global__ __launch_bounds__(256) void gemm_zr_mfma(
    const unsigned short* __restrict__ XHp, const unsigned short* __restrict__ P1p,
    const unsigned short* __restrict__ P2p,
    const unsigned short* __restrict__ Wf, const float* __restrict__ bz,
    const float* __restrict__ br, const float* __restrict__ H,
    float* __restrict__ Zf, unsigned short* __restrict__ HR, int n) {
    int tid = threadIdx.x;
    int lane = tid & 63;
    int ngrp = tid >> 6;
    int rowbase = blockIdx.x * 64;
    int lr = lane & 15, quad = lane >> 4;

    int tiles[4];
#pragma unroll
    for (int mt = 0; mt < 4; ++mt) {
        int t = (rowbase >> 4) + mt;
        tiles[mt] = (t > N_TILES - 1) ? N_TILES - 1 : t;
    }

    f32x4 zero = {0.f, 0.f, 0.f, 0.f};
    f32x4 acc[4][2];
#pragma unroll
    for (int a = 0; a < 4; ++a)
#pragma unroll
        for (int b = 0; b < 2; ++b) acc[a][b] = zero;

#pragma unroll
    for (int ks = 0; ks < 20; ++ks) {
        const unsigned short* T = (ks < 4) ? XHp : (ks < 12) ? P1p : P2p;
        int ck = (ks < 4) ? ks : (ks < 12) ? ks - 4 : ks - 12;
        int nck = (ks < 4) ? 4 : 8;
        bf8 b0 = *(const bf8*)(Wf + (((size_t)ks * 8 + ngrp * 2 + 0) * 64 + lane) * 8);
        bf8 b1 = *(const bf8*)(Wf + (((size_t)ks * 8 + ngrp * 2 + 1) * 64 + lane) * 8);
#pragma unroll
        for (int mt = 0; mt < 4; ++mt) {
            bf8 a = *(const bf8*)(T + (((size_t)tiles[mt] * nck + ck) * 64 + lane) * 8);
            acc[mt][0] = __builtin_amdgcn_mfma_f32_16x16x32_bf16(a, b0, acc[mt][0], 0, 0, 0);
            acc[mt][1] = __builtin_amdgcn_mfma_f32_16x16x32_bf16(a, b1, acc[mt][1], 0, 0, 0);
        }
    }
#pragma unroll
    for (int mt = 0; mt < 4; ++mt)
#pragma unroll
        for (int reg = 0; reg < 4; ++reg) {
            int r = rowbase + mt * 16 + quad * 4 + reg;
            if (r >= n) continue;
#pragma unroll
            for (int nt = 0; nt < 2; ++nt) {
                int cidx = ngrp * 32 + nt * 16 + lr;
                float bias = (cidx < 64) ? bz[cidx] : br[cidx - 64];
                float v = acc[mt][nt][reg] + bias;
                float s = 1.f / (1.f + expf(-v));
                if (cidx < 64) {
                    Zf[(size_t)r * 64 + cidx] = s;
                } else {
                    int c2 = cidx - 64;
                    HR[(size_t)r * 64 + c2] = f2bfu(H[(size_t)r * 64 + c2] * s);
                }
            }
        }
}

__global__ __launch_bounds__(256) void gemm_h_mfma(
    const unsigned short* __restrict__ XHp, const unsigned short* __restrict__ P1p,
    const unsigned short* __restrict__ P2p, const unsigned short* __restrict__ HR,
    const unsigned short* __restrict__ Q1p, const unsigned short* __restrict__ Q2p,
    const unsigned short* __restrict__ Wf, const float* __restrict__ bh,
    const float* __restrict__ Zf, const float* __restrict__ H,
    float* __restrict__ out, int n) {
    int tid = threadIdx.x;
    int lane = tid & 63;
    int wid = tid >> 6;
    int mh = wid & 1, ngrp = wid >> 1;
    int rowbase = blockIdx.x * 128 + mh * 64;
    int lr = lane & 15, quad = lane >> 4;

    int tiles[4];
    const unsigned short* hrp[4];
#pragma unroll
    for (int mt = 0; mt < 4; ++mt) {
        int t = (rowbase >> 4) + mt;
        tiles[mt] = (t > N_TILES - 1) ? N_TILES - 1 : t;
        int r = rowbase + mt * 16 + lr;
        if (r >= n) r = n - 1;
        hrp[mt] = HR + (size_t)r * 64 + quad * 8;
    }

    f32x4 zero = {0.f, 0.f, 0.f, 0.f};
    f32x4 acc[4][2];
#pragma unroll
    for (int a = 0; a < 4; ++a)
#pragma unroll
        for (int b = 0; b < 2; ++b) acc[a][b] = zero;

#pragma unroll
    for (int ks = 0; ks < 20; ++ks) {
        bf8 b0 = *(const bf8*)(Wf + (((size_t)ks * 4 + ngrp * 2 + 0) * 64 + lane) * 8);
        bf8 b1 = *(const bf8*)(Wf + (((size_t)ks * 4 + ngrp * 2 + 1) * 64 + lane) * 8);
#pragma unroll
        for (int mt = 0; mt < 4; ++mt) {
            bf8 a;
            if (ks == 10 || ks == 11) {
                a = *(const bf8*)(hrp[mt] + (ks - 10) * 32);
            } else {
                const unsigned short* T = (ks < 2) ? XHp : (ks < 6) ? P1p :
                                          (ks < 10) ? P2p : (ks < 16) ? Q1p : Q2p;
                int ck = (ks < 2) ? ks : (ks < 6) ? ks - 2 : (ks < 10) ? ks - 6 :
                         (ks < 16) ? ks - 12 : ks - 16;
                int nck = (ks < 2) ? 4 : (ks < 10) ? 8 : 4;
                a = *(const bf8*)(T + (((size_t)tiles[mt] * nck + ck) * 64 + lane) * 8);
            }
            acc[mt][0] = __builtin_amdgcn_mfma_f32_16x16x32_bf16(a, b0, acc[mt][0], 0, 0, 0);
            acc[mt][1] = __builtin_amdgcn_mfma_f32_16x16x32_bf16(a, b1, acc[mt][1], 0, 0, 0);
        }
    }
#pragma unroll
    for (int mt = 0; mt < 4; ++mt)
#pragma unroll
        for (int reg = 0; reg < 4; ++reg) {
            int r = rowbase + mt * 16 + quad * 4 + reg;
            if (r >= n) continue;
#pragma unroll
            for (int nt = 0; nt < 2; ++nt) {
                int cidx = ngrp * 32 + nt * 16 + lr;
                float ht = tanhf(acc[mt][nt][reg] + bh[cidx]);
                float z = Zf[(size_t)r * 64 + cidx];
                float h_old = H[(size_t)r * 64 + cidx];
                out[(size_t)r * 64 + cidx] = z * h_old + (1.f - z) * ht;
            }
        }
}

// ---------------- launch ----------------

static inline size_t rup(size_t x) { return (x + 63) & ~(size_t)63; }

extern "C" void kernel_launch(void* const* d_in, const int* in_sizes, int n_in,
                              void* d_out, int out_size, void* d_ws, size_t ws_size,
                              hipStream_t stream) {
    const float* X  = (const float*)d_in[0];
    const int*   EI = (const int*)d_in[1];
    const float* H  = (const float*)d_in[2];
    const float* Wz = (const float*)d_in[3];
    const float* bz = (const float*)d_in[4];
    const float* Wr = (const float*)d_in[5];
    const float* br = (const float*)d_in[6];
    const float* Wh = (const float*)d_in[7];
    const float* bh = (const float*)d_in[8];
    float* out = (float*)d_out;

    const int* row = EI;
    const int* col = EI + N_EDGES;

    char* ws = (char*)d_ws;
    size_t off = 0;
    auto carve = [&](size_t bytes) { void* p = ws + off; off += rup(bytes); return p; };

    int*   deg_out   = (int*)carve(N_NODES * 4);
    int*   deg_in    = (int*)carve(N_NODES * 4);
    int*   rowptr    = (int*)carve((N_NODES + 1) * 4);
    int*   cursor    = (int*)carve(N_NODES * 4);
    int*   blocksums = (int*)carve(64 * 4);
    float2* winv     = (float2*)carve(N_NODES * 8);
    int*   csr_src   = (int*)carve(N_EDGES * 4);
    float2* csr_w    = (float2*)carve(N_EDGES * 8);
    unsigned short* XH  = (unsigned short*)carve((size_t)N_NODES * 128 * 2);   // row-major
    unsigned short* XHs = (unsigned short*)carve((size_t)N_NODES * 128 * 2);   // slice-major (4)
    unsigned short* P1g = (unsigned short*)carve((size_t)N_NODES * 256 * 2);   // slice-major (8)
    unsigned short* XHp = (unsigned short*)carve((size_t)N_TILES * 4 * 512 * 2);
    unsigned short* P1p = (unsigned short*)carve((size_t)N_TILES * 8 * 512 * 2);
    unsigned short* P2p = (unsigned short*)carve((size_t)N_TILES * 8 * 512 * 2);
    unsigned short* HR  = (unsigned short*)carve((size_t)N_NODES * 64 * 2);
    float* Zf           = (float*)carve((size_t)N_NODES * 64 * 4);
    unsigned short* Wzrf = (unsigned short*)carve(20 * 8 * 64 * 8 * 2);
    unsigned short* Whf  = (unsigned short*)carve(20 * 4 * 64 * 8 * 2);

    // Aliases (dead after prop2_128s / gemm_zr):
    unsigned short* Q1  = XH;                                  // [n][128] row-major (XH dead after prop2_128s? no - XH needed by prop2_128s only; Q1 written after)
    unsigned short* Q1p = P1g;                                 // packed, 12.8 MB
    unsigned short* Q2p = P1g + (size_t)N_TILES * 4 * 512;     // packed, 12.8 MB

    hipMemsetAsync(deg_out, 0, rup(N_NODES * 4) + rup(N_NODES * 4), stream);
    count_deg<<<(N_EDGES + 255) / 256, 256, 0, stream>>>(row, col, deg_out, deg_in, N_EDGES);

    int nblk = (N_NODES + 1023) / 1024;
    scan_block<<<nblk, 1024, 0, stream>>>(deg_in, rowptr, blocksums, N_NODES);
    scan_sums<<<1, 64, 0, stream>>>(blocksums, nblk);
    scan_add<<<(N_NODES + 1 + 255) / 256, 256, 0, stream>>>(rowptr, blocksums, cursor,
                                                            deg_out, deg_in, winv, N_NODES, N_EDGES);

    // fused: build_csr + concat_xh (row/packed/sliced) + pack_weights
    fused_prep<<<CSR_BLOCKS + CONCAT_BLOCKS + PACK_BLOCKS, 256, 0, stream>>>(
        row, col, winv, cursor, csr_src, csr_w,
        X, H, XH, XHp, XHs, Wz, Wr, Wh, Wzrf, Whf, N_NODES, N_EDGES);

    // sliced props on XH (XCD-pinned slices)
    prop1_128s<<<4 * NODE_CHUNKS, 256, 0, stream>>>(XHs, rowptr, csr_src, csr_w,
                                                    P1g, P1p, N_NODES);
    prop2_128s<<<8 * NODE_CHUNKS, 256, 0, stream>>>(P1g, XH, rowptr, csr_src, csr_w,
                                                    P2p, N_NODES);

    // Z|R GEMM -> Zf, HR
    int zr_blocks = (N_NODES + 63) / 64;
    gemm_zr_mfma<<<zr_blocks, 256, 0, stream>>>(XHp, P1p, P2p, Wzrf, bz, br, H, Zf, HR, N_NODES);

    // props on HR: 4 nodes/wave (Q1 aliases XH; Q1p/Q2p alias P1g - all dead now)
    int blocks_p64 = (((N_NODES + 3) / 4) * 64 + 255) / 256;
    prop1_64<<<blocks_p64, 256, 0, stream>>>(HR, rowptr, csr_src, csr_w, Q1, Q1p, N_NODES);
    prop2_64<<<blocks_p64, 256, 0, stream>>>(Q1, HR, rowptr, csr_src, csr_w, Q2p, N_NODES);

    // H~ GEMM + GRU mix -> out
    int h_blocks = (N_NODES + 127) / 128;
    gemm_h_mfma<<<h_blocks, 256, 0, stream>>>(XHp, P1p, P2p, HR, Q1p, Q2p,
                                              Whf, bh, Zf, H, out, N_NODES);
}